// Round 12
// baseline (84.207 us; speedup 1.0000x reference)
//
#include <hip/hip_runtime.h>
#include <math.h>

// LatentSDE (L=C=D=1, H=64), all nets tabulated, thread-per-b recurrence.
// R11 lesson: the scan scales with ACTIVE SIMD COUNT (per-wave issue ~100
// insts dominates; 2 waves/SIMD on 16 CUs was SLOWER than 1 wave/SIMD on 32).
// R12: max spread -- 128 blocks x 64 threads = 128 CUs, one wave each,
// 90KB two-tier LDS table per block (R10/R11-verified layout + numerics).

#define B_SZ 8192
#define T_SZ 128
#define NBLK 128                 // scan blocks (64 thr each)

// float offsets (16B aligned) -- layout identical to R10/R11 (verified)
#define FQ1_OFF  0                // 2049*4 = 8196
#define HGP1_OFF 8196             // 1025*4 = 4100
#define FQ2_OFF  12296            // 1025*4 = 4100
#define HGP2_OFF 16396            // 1025*4 = 4100
#define ET2_OFF  20496            // 1024*2 = 2048
#define TAB_FLOATS 22544          // 90,176 B
// float4 indices
#define FQ1_I  0
#define HGP1_I 2049
#define FQ2_I  3074
#define HGP2_I 4099

#define NF1 2049
#define NH1 1025
#define NF2 1025
#define NH2 1025
#define NEE 1024
#define NENT (NF1+NH1+NF2+NH2+NEE)   // 6148 entries, one wave each

#define NXI 1024
#define XSF 64.0f
#define XOF 512.0f

#if __has_builtin(__builtin_amdgcn_rcpf)
#define RCPF(x) __builtin_amdgcn_rcpf(x)
#else
#define RCPF(x) (1.0f / (x))
#endif
#if __has_builtin(__builtin_amdgcn_sqrtf)
#define SQRTF(x) __builtin_amdgcn_sqrtf(x)
#else
#define SQRTF(x) sqrtf(x)
#endif

__device__ __forceinline__ float sp_precise(float a) {
  return fmaxf(a, 0.0f) + log1pf(expf(-fabsf(a)));
}
__device__ __forceinline__ float wsum64(float v) {
  #pragma unroll
  for (int m = 1; m <= 32; m <<= 1) v += __shfl_xor(v, m);
  return v;
}

// ---------------- build: one wave per table entry (R11-verified) ----------------
__global__ __launch_bounds__(256) void build_tabs(
    const float* __restrict__ ew1, const float* __restrict__ eb1,
    const float* __restrict__ ew2, const float* __restrict__ eb2,
    const float* __restrict__ fw1, const float* __restrict__ fb1,
    const float* __restrict__ fw2, const float* __restrict__ fb2,
    const float* __restrict__ hw1, const float* __restrict__ hb1,
    const float* __restrict__ hw2, const float* __restrict__ hb2,
    const float* __restrict__ gw1, const float* __restrict__ gb1,
    const float* __restrict__ gw2, const float* __restrict__ gb2,
    const float* __restrict__ pw1, const float* __restrict__ pb1,
    const float* __restrict__ pw2, const float* __restrict__ pb2,
    float* __restrict__ tabs, int* __restrict__ ctr)
{
  const int gtid = blockIdx.x * 256 + threadIdx.x;
  if (gtid == 0) *ctr = 0;
  const int ent  = gtid >> 6;          // wave id == entry id
  const int lane = threadIdx.x & 63;
  if (ent >= NENT) return;

  if (ent < NF1 + NH1 + NF2 + NH2) {
    bool isF; float z; int idx4;
    if (ent < NF1)                { isF = true;  z = -128.0f + (float)ent * 0.125f;            idx4 = FQ1_I + ent; }
    else if (ent < NF1+NH1)       { isF = false; z = -128.0f + (float)(ent-NF1) * 0.25f;       idx4 = HGP1_I + (ent-NF1); }
    else if (ent < NF1+NH1+NF2)   { isF = true;  z = -8192.0f + (float)(ent-NF1-NH1) * 16.0f;  idx4 = FQ2_I + (ent-NF1-NH1); }
    else                          { isF = false; z = -8192.0f + (float)(ent-NF1-NH1-NF2) * 16.0f; idx4 = HGP2_I + (ent-NF1-NH1-NF2); }

    if (isF) {   // f at c-nodes {-3,-1,1,3}; lane = unit
      const float az = fmaf(z, fw1[lane], fb1[lane]);
      const float wc = fw1[64 + lane], w2 = fw2[lane];
      float s0 = sp_precise(fmaf(-3.0f, wc, az)) * w2;
      float s1 = sp_precise(fmaf(-1.0f, wc, az)) * w2;
      float s2 = sp_precise(fmaf( 1.0f, wc, az)) * w2;
      float s3 = sp_precise(fmaf( 3.0f, wc, az)) * w2;
      s0 = wsum64(s0); s1 = wsum64(s1); s2 = wsum64(s2); s3 = wsum64(s3);
      if (lane == 0) {
        const float fb = fb2[0];
        ((float4*)tabs)[idx4] = make_float4(s0 + fb, s1 + fb, s2 + fb, s3 + fb);
      }
    } else {     // h, g, p
      float sh = sp_precise(fmaf(z, hw1[lane], hb1[lane])) * hw2[lane];
      float sg = sp_precise(fmaf(z, gw1[lane], gb1[lane])) * gw2[lane];
      float sp = sp_precise(fmaf(z, pw1[lane], pb1[lane])) * pw2[lane];
      sh = wsum64(sh); sg = wsum64(sg); sp = wsum64(sp);
      if (lane == 0) {
        ((float4*)tabs)[idx4] = make_float4(
            sh + hb2[0],
            1.0f / (1.0f + expf(-(sg + gb2[0]))),
            sp + pb2[0], 0.0f);
      }
    }
  } else {
    const int i = ent - (NF1 + NH1 + NF2 + NH2);
    const float x0 = -8.0f + (float)i * (1.0f / 64.0f);
    const float x1 = x0 + (1.0f / 64.0f);
    const float w = ew1[lane], bb = eb1[lane], w2 = ew2[lane];
    float s0 = sp_precise(fmaf(x0, w, bb)) * w2;
    float s1 = sp_precise(fmaf(x1, w, bb)) * w2;
    s0 = wsum64(s0); s1 = wsum64(s1);
    if (lane == 0) {
      const float eb = eb2[0];
      ((float2*)(tabs + ET2_OFF))[i] = make_float2(s0 + eb, s1 + eb);
    }
  }
}

// ---------------- scan: thread-per-b, 128 CUs, LDS tables ----------------
__global__ __launch_bounds__(64) void sde_scan(
    const float* __restrict__ xs, const float* __restrict__ ts,
    const float* __restrict__ noise_std, const float* __restrict__ eps0,
    const float* __restrict__ dW,
    const float* __restrict__ qw,  const float* __restrict__ qb,
    const float* __restrict__ fw1, const float* __restrict__ fb1,
    const float* __restrict__ fw2, const float* __restrict__ fb2,
    const float* __restrict__ hw1, const float* __restrict__ hb1,
    const float* __restrict__ hw2, const float* __restrict__ hb2,
    const float* __restrict__ gw1, const float* __restrict__ gb1,
    const float* __restrict__ gw2, const float* __restrict__ gb2,
    const float* __restrict__ pw1, const float* __restrict__ pb1,
    const float* __restrict__ pw2, const float* __restrict__ pb2,
    const float* __restrict__ pz0_mean, const float* __restrict__ pz0_logstd,
    const float* __restrict__ tabsrc,
    int* __restrict__ ctr, float* __restrict__ partA, float* __restrict__ partB,
    float* __restrict__ out)
{
  __shared__ __align__(16) float tab[TAB_FLOATS];
  __shared__ float la[64], lb[64];
  __shared__ int lastflag;

  const int tid = threadIdx.x;
  const int b   = blockIdx.x * 64 + tid;

  { // stage all tables (float4-wise)
    const float4* s4 = (const float4*)tabsrc;
    float4* d4 = (float4*)tab;
    for (int i = tid; i < TAB_FLOATS / 4; i += 64) d4[i] = s4[i];
  }
  __syncthreads();

  const float4* tab4 = (const float4*)tab;
  const float2* et2  = (const float2*)(tab + ET2_OFF);

  const float fb2s = fb2[0], hb2s = hb2[0], gb2s = gb2[0], pb2s = pb2[0];
  const float qw0 = qw[0], qw1 = qw[1], qb0 = qb[0], qb1 = qb[1];
  const float ns = noise_std[0];
  const float inv_ns = 1.0f / ns;
  const float nh_i2 = -0.5f * inv_ns * inv_ns;
  const float pm = pz0_mean[0], pls = pz0_logstd[0];

  auto einterp = [&](float x) {
    const float s = fmaf(x, XSF, XOF);
    const float sc = fminf(fmaxf(s, 0.0f), (float)(NXI - 1));
    const int i = (int)sc;
    const float fr = s - (float)i;
    const float2 e = et2[i];
    return fmaf(fr, e.y - e.x, e.x);
  };
  auto lagr = [&](float c) {    // cubic Lagrange, nodes {-3,-1,1,3}
    const float c2 = c * c;
    const float p1 = c2 - 1.0f, p3 = c2 - 9.0f;
    return make_float4(p1 * (c - 3.0f) * (-1.0f / 48.0f),
                       p3 * (c - 1.0f) * ( 1.0f / 16.0f),
                       p3 * (c + 1.0f) * (-1.0f / 16.0f),
                       p1 * (c + 3.0f) * ( 1.0f / 48.0f));
  };
  auto hgp_exact = [&](float z, float& hv, float& gv, float& pv) {
    float sh = 0.f, sg = 0.f, sp = 0.f;
    for (int j = 0; j < 64; ++j) {
      sh = fmaf(sp_precise(fmaf(z, hw1[j], hb1[j])), hw2[j], sh);
      sg = fmaf(sp_precise(fmaf(z, gw1[j], gb1[j])), gw2[j], sg);
      sp = fmaf(sp_precise(fmaf(z, pw1[j], pb1[j])), pw2[j], sp);
    }
    hv = sh + hb2s;
    gv = 1.0f / (1.0f + expf(-(sg + gb2s)));
    pv = sp + pb2s;
  };
  auto f_exact = [&](float z, float c) {
    float s = 0.f;
    for (int j = 0; j < 64; ++j)
      s = fmaf(sp_precise(fmaf(z, fw1[j], fmaf(c, fw1[64 + j], fb1[j]))), fw2[j], s);
    return s + fb2s;
  };

  // two-tier index (R10/R11-verified)
  auto zidx = [&](float z, int& fqi, float& fqf, int& hgi, float& hgf, bool& inr) {
    const float s1 = fmaf(z, 8.0f, 1024.0f);        // tier1 f grid
    const float s2 = fmaf(z, 0.0625f, 512.0f);      // tier2 grid (dz=16)
    const bool t1 = (s1 >= 0.0f) && (s1 <= 2048.0f);
    const bool t2 = (s2 >= 0.0f) && (s2 <= 1024.0f);
    inr = t1 || t2;
    const float sf = t1 ? s1 : fminf(fmaxf(s2, 0.0f), 1024.0f);
    int fi = min((int)sf, t1 ? 2047 : 1023);
    fqi = (t1 ? FQ1_I : FQ2_I) + fi;
    fqf = sf - (float)fi;
    const float sh = t1 ? fmaf(z, 4.0f, 512.0f) : sf;
    int hi = min((int)sh, 1023);
    hgi = (t1 ? HGP1_I : HGP2_I) + hi;
    hgf = sh - (float)hi;
  };

  // ---- prologue ----
  const float x0 = xs[b];
  float x1 = xs[B_SZ + b];
  float x2 = xs[2 * B_SZ + b];
  const float c0v = einterp(x0);
  float c_cur = einterp(x1);
  float c_nxt = einterp(x2);
  const float qm  = fmaf(c0v, qw0, qb0);
  const float qls = fmaf(c0v, qw1, qb1);
  float z = fmaf(__expf(qls), eps0[b], qm);
  const float dqm = qm - pm;
  const float kl = (pls - qls)
                 + (__expf(2.0f * qls) + dqm * dqm) * (0.5f * __expf(-2.0f * pls))
                 - 0.5f;

  bool zin; int fqi, hgi; float fqf, hgf;
  float4 q0, q1; float hv, gv, pv;
  zidx(z, fqi, fqf, hgi, hgf, zin);
  q0 = tab4[fqi]; q1 = tab4[fqi + 1];
  {
    const float4 a = tab4[hgi], bq = tab4[hgi + 1];
    if (zin) {
      hv = fmaf(hgf, bq.x - a.x, a.x);
      gv = fmaf(hgf, bq.y - a.y, a.y);
      pv = fmaf(hgf, bq.z - a.z, a.z);
    } else {
      hgp_exact(z, hv, gv, pv);
    }
  }
  float lp_sum; { const float d = x0 - pv; lp_sum = nh_i2 * d * d; }
  float lr_sum = 0.0f;
  float dw_cur = dW[b];
  float dw_n1  = dW[B_SZ + b];
  float4 L = lagr(c_cur);
  bool cin = fabsf(c_cur) <= 3.0f;

  // ---- Euler-Maruyama scan ----
  for (int k = 0; k < T_SZ - 1; ++k) {
    const int   i3    = (k + 3 < T_SZ) ? (k + 3) : (T_SZ - 1);
    const float x3    = xs[i3 * B_SZ + b];
    const float dw_n2 = (k + 2 < T_SZ - 1) ? dW[(k + 2) * B_SZ + b] : 0.0f;
    const float dt    = ts[k + 1] - ts[k];
    const float sq    = SQRTF(dt);

    // f(z, c_cur): z-lerp of 4 c-nodes then cubic in c
    float fv;
    if (zin && cin) {
      const float n0 = fmaf(fqf, q1.x - q0.x, q0.x);
      const float n1 = fmaf(fqf, q1.y - q0.y, q0.y);
      const float n2 = fmaf(fqf, q1.z - q0.z, q0.z);
      const float n3 = fmaf(fqf, q1.w - q0.w, q0.w);
      fv = n0 * L.x + n1 * L.y + n2 * L.z + n3 * L.w;
    } else {
      fv = f_exact(z, c_cur);
    }

    const float gvs = fmaxf(gv, 1e-6f);
    const float uu = (fv - hv) * RCPF(gvs);   // rcp feeds only lr_sum (off z-chain)
    lr_sum = fmaf((0.5f * dt) * uu, uu, lr_sum);
    z = fmaf(gvs * dw_cur, sq, fmaf(fv, dt, z));

    // re-index at new z; issue all 4 gathers together
    zidx(z, fqi, fqf, hgi, hgf, zin);
    q0 = tab4[fqi]; q1 = tab4[fqi + 1];
    const float4 a = tab4[hgi], bq = tab4[hgi + 1];
    if (zin) {
      hv = fmaf(hgf, bq.x - a.x, a.x);
      gv = fmaf(hgf, bq.y - a.y, a.y);
      pv = fmaf(hgf, bq.z - a.z, a.z);
    } else {
      hgp_exact(z, hv, gv, pv);
    }

    // projector likelihood at t=k+1
    const float d = x1 - pv;
    lp_sum = fmaf(nh_i2 * d, d, lp_sum);

    // advance off-chain pipelines
    c_cur = c_nxt; L = lagr(c_cur); cin = fabsf(c_cur) <= 3.0f;
    c_nxt = einterp(x3);
    x1 = x2; x2 = x3;
    dw_cur = dw_n1; dw_n1 = dw_n2;
  }

  // ---- fused deterministic reduction ----
  la[tid] = lp_sum; lb[tid] = kl + lr_sum;
  __syncthreads();
  for (int s = 32; s > 0; s >>= 1) {
    if (tid < s) { la[tid] += la[tid + s]; lb[tid] += lb[tid + s]; }
    __syncthreads();
  }
  if (tid == 0) {
    partA[blockIdx.x] = la[0]; partB[blockIdx.x] = lb[0];
    __threadfence();
    lastflag = (atomicAdd(ctr, 1) == NBLK - 1) ? 1 : 0;
  }
  __syncthreads();
  if (lastflag) {
    __threadfence();
    float sa = partA[tid] + partA[tid + 64];
    float sb = partB[tid] + partB[tid + 64];
    la[tid] = sa; lb[tid] = sb;
    __syncthreads();
    for (int s = 32; s > 0; s >>= 1) {
      if (tid < s) { la[tid] += la[tid + s]; lb[tid] += lb[tid + s]; }
      __syncthreads();
    }
    if (tid == 0) {
      out[0] = la[0] / (float)B_SZ
             + (float)T_SZ * (-__logf(ns) - 0.9189385332046727f);
      out[1] = lb[0] / (float)B_SZ;
    }
  }
}

extern "C" void kernel_launch(void* const* d_in, const int* in_sizes, int n_in,
                              void* d_out, int out_size, void* d_ws, size_t ws_size,
                              hipStream_t stream) {
  const float* xs        = (const float*)d_in[0];
  const float* ts        = (const float*)d_in[1];
  const float* noise_std = (const float*)d_in[2];
  const float* eps0      = (const float*)d_in[3];
  const float* dW        = (const float*)d_in[4];
  const float* ew1 = (const float*)d_in[5];
  const float* eb1 = (const float*)d_in[6];
  const float* ew2 = (const float*)d_in[7];
  const float* eb2 = (const float*)d_in[8];
  const float* qw  = (const float*)d_in[9];
  const float* qb  = (const float*)d_in[10];
  const float* fw1 = (const float*)d_in[11];
  const float* fb1 = (const float*)d_in[12];
  const float* fw2 = (const float*)d_in[13];
  const float* fb2 = (const float*)d_in[14];
  const float* hw1 = (const float*)d_in[15];
  const float* hb1 = (const float*)d_in[16];
  const float* hw2 = (const float*)d_in[17];
  const float* hb2 = (const float*)d_in[18];
  const float* gw1 = (const float*)d_in[19];
  const float* gb1 = (const float*)d_in[20];
  const float* gw2 = (const float*)d_in[21];
  const float* gb2 = (const float*)d_in[22];
  const float* pw1 = (const float*)d_in[23];
  const float* pb1 = (const float*)d_in[24];
  const float* pw2 = (const float*)d_in[25];
  const float* pb2 = (const float*)d_in[26];
  const float* pz0_mean   = (const float*)d_in[27];
  const float* pz0_logstd = (const float*)d_in[28];
  float* out = (float*)d_out;

  float* tabs  = (float*)d_ws;                  // [TAB_FLOATS]
  int*   ctr   = (int*)(tabs + TAB_FLOATS);     // [1] (+pad)
  float* partA = tabs + TAB_FLOATS + 4;         // [NBLK]
  float* partB = partA + NBLK;                  // [NBLK]

  build_tabs<<<(NENT * 64 + 255) / 256, 256, 0, stream>>>(
      ew1, eb1, ew2, eb2, fw1, fb1, fw2, fb2,
      hw1, hb1, hw2, hb2, gw1, gb1, gw2, gb2,
      pw1, pb1, pw2, pb2, tabs, ctr);

  sde_scan<<<NBLK, 64, 0, stream>>>(
      xs, ts, noise_std, eps0, dW, qw, qb,
      fw1, fb1, fw2, fb2, hw1, hb1, hw2, hb2,
      gw1, gb1, gw2, gb2, pw1, pb1, pw2, pb2,
      pz0_mean, pz0_logstd, tabs, ctr, partA, partB, out);
}

// Round 13
// 73.849 us; speedup vs baseline: 1.1403x; 1.1403x over previous
//
#include <hip/hip_runtime.h>
#include <math.h>

// LatentSDE (L=C=D=1, H=64), all nets tabulated, thread-per-b recurrence.
// R10/R11/R12 geometry sweep: 256-thr blocks (R10) empirically best; per-step
// issue (~90 VALU) + unhidden waits dominate. R13 cuts per-step work:
//  - ONE merged 32B LDS entry {f(-3),f(-1),f(1),f(3), h,g,p,pad}: one index,
//    one base, 4x ds_read_b128 at imm offsets (64B contiguous for zi,zi+1)
//  - encoder hoisted to a parallel pre-pass writing ctx[t,b] (4MB ws)
//  - et2 out of scan LDS; scan loop ~55 insts/step
// Tiers (verified R10-12): tier1 z[-128,128] dz=1/8; tier2 z[-8192,8192]
// dz=16; exact-MLP fallback beyond (rare). absmax was 0.0 for 3 rounds.

#define B_SZ 8192
#define T_SZ 128
#define NBLK 32                  // scan blocks (256 thr each)

#define NT1 2049                 // tier1 entries (z in [-128,128], dz=1/8)
#define NT2 1025                 // tier2 entries (z in [-8192,8192], dz=16)
#define NEE 1024                 // encoder pairs (x in [-8,8], dx=1/64)
#define NENT (NT1 + NT2 + NEE)   // 4098 build entries (one wave each)

#define MT_FLOATS (8 * (NT1 + NT2))   // 24592 floats of merged z-table
#define ET2G_OFF  MT_FLOATS           // et2 (global only), 2048 floats
#define TABG_FLOATS (MT_FLOATS + 2048)  // 26640
#define T2_BASE4 (2 * NT1)            // tier2 float4 base index = 4098

#define NXI 1024
#define XSF 64.0f
#define XOF 512.0f

#if __has_builtin(__builtin_amdgcn_rcpf)
#define RCPF(x) __builtin_amdgcn_rcpf(x)
#else
#define RCPF(x) (1.0f / (x))
#endif
#if __has_builtin(__builtin_amdgcn_sqrtf)
#define SQRTF(x) __builtin_amdgcn_sqrtf(x)
#else
#define SQRTF(x) sqrtf(x)
#endif

__device__ __forceinline__ float sp_precise(float a) {
  return fmaxf(a, 0.0f) + log1pf(expf(-fabsf(a)));
}
__device__ __forceinline__ float wsum64(float v) {
  #pragma unroll
  for (int m = 1; m <= 32; m <<= 1) v += __shfl_xor(v, m);
  return v;
}

// ---------------- build: one wave per entry ----------------
__global__ __launch_bounds__(256) void build_tabs(
    const float* __restrict__ ew1, const float* __restrict__ eb1,
    const float* __restrict__ ew2, const float* __restrict__ eb2,
    const float* __restrict__ fw1, const float* __restrict__ fb1,
    const float* __restrict__ fw2, const float* __restrict__ fb2,
    const float* __restrict__ hw1, const float* __restrict__ hb1,
    const float* __restrict__ hw2, const float* __restrict__ hb2,
    const float* __restrict__ gw1, const float* __restrict__ gb1,
    const float* __restrict__ gw2, const float* __restrict__ gb2,
    const float* __restrict__ pw1, const float* __restrict__ pb1,
    const float* __restrict__ pw2, const float* __restrict__ pb2,
    float* __restrict__ tabs, int* __restrict__ ctr)
{
  const int gtid = blockIdx.x * 256 + threadIdx.x;
  if (gtid == 0) *ctr = 0;
  const int ent  = gtid >> 6;
  const int lane = threadIdx.x & 63;
  if (ent >= NENT) return;

  if (ent < NT1 + NT2) {
    // merged z-entry: {f(-3),f(-1),f(1),f(3)} and {h, sigmoid(g), p, 0}
    const bool t1 = ent < NT1;
    const int  i  = t1 ? ent : (ent - NT1);
    const float z = t1 ? (-128.0f + (float)i * 0.125f)
                       : (-8192.0f + (float)i * 16.0f);
    const int base4 = (t1 ? 0 : T2_BASE4) + 2 * i;

    const float az = fmaf(z, fw1[lane], fb1[lane]);
    const float wc = fw1[64 + lane], w2 = fw2[lane];
    float s0 = sp_precise(fmaf(-3.0f, wc, az)) * w2;
    float s1 = sp_precise(fmaf(-1.0f, wc, az)) * w2;
    float s2 = sp_precise(fmaf( 1.0f, wc, az)) * w2;
    float s3 = sp_precise(fmaf( 3.0f, wc, az)) * w2;
    float sh = sp_precise(fmaf(z, hw1[lane], hb1[lane])) * hw2[lane];
    float sg = sp_precise(fmaf(z, gw1[lane], gb1[lane])) * gw2[lane];
    float sp = sp_precise(fmaf(z, pw1[lane], pb1[lane])) * pw2[lane];
    s0 = wsum64(s0); s1 = wsum64(s1); s2 = wsum64(s2); s3 = wsum64(s3);
    sh = wsum64(sh); sg = wsum64(sg); sp = wsum64(sp);
    if (lane == 0) {
      const float fb = fb2[0];
      ((float4*)tabs)[base4]     = make_float4(s0 + fb, s1 + fb, s2 + fb, s3 + fb);
      ((float4*)tabs)[base4 + 1] = make_float4(
          sh + hb2[0],
          1.0f / (1.0f + expf(-(sg + gb2[0]))),
          sp + pb2[0], 0.0f);
    }
  } else {
    const int i = ent - (NT1 + NT2);
    const float x0 = -8.0f + (float)i * (1.0f / 64.0f);
    const float x1 = x0 + (1.0f / 64.0f);
    const float w = ew1[lane], bb = eb1[lane], w2 = ew2[lane];
    float s0 = sp_precise(fmaf(x0, w, bb)) * w2;
    float s1 = sp_precise(fmaf(x1, w, bb)) * w2;
    s0 = wsum64(s0); s1 = wsum64(s1);
    if (lane == 0) {
      const float eb = eb2[0];
      ((float2*)(tabs + ET2G_OFF))[i] = make_float2(s0 + eb, s1 + eb);
    }
  }
}

// ---------------- pre-pass: ctx[t,b] = enc(xs[t,b]) via global et2 ----------------
__global__ __launch_bounds__(256) void ctx_pre(
    const float* __restrict__ xs, const float* __restrict__ tabs,
    float* __restrict__ ctx)
{
  const int i = blockIdx.x * 256 + threadIdx.x;
  const float2* et2 = (const float2*)(tabs + ET2G_OFF);
  const float s = fmaf(xs[i], XSF, XOF);
  const float sc = fminf(fmaxf(s, 0.0f), (float)(NXI - 1));
  const int ii = (int)sc;
  const float fr = s - (float)ii;
  const float2 e = et2[ii];
  ctx[i] = fmaf(fr, e.y - e.x, e.x);
}

// ---------------- scan: thread-per-b, merged LDS table ----------------
__global__ __launch_bounds__(256) void sde_scan(
    const float* __restrict__ xs, const float* __restrict__ ts,
    const float* __restrict__ noise_std, const float* __restrict__ eps0,
    const float* __restrict__ dW, const float* __restrict__ ctx,
    const float* __restrict__ qw,  const float* __restrict__ qb,
    const float* __restrict__ fw1, const float* __restrict__ fb1,
    const float* __restrict__ fw2, const float* __restrict__ fb2,
    const float* __restrict__ hw1, const float* __restrict__ hb1,
    const float* __restrict__ hw2, const float* __restrict__ hb2,
    const float* __restrict__ gw1, const float* __restrict__ gb1,
    const float* __restrict__ gw2, const float* __restrict__ gb2,
    const float* __restrict__ pw1, const float* __restrict__ pb1,
    const float* __restrict__ pw2, const float* __restrict__ pb2,
    const float* __restrict__ pz0_mean, const float* __restrict__ pz0_logstd,
    const float* __restrict__ tabsrc,
    int* __restrict__ ctr, float* __restrict__ partA, float* __restrict__ partB,
    float* __restrict__ out)
{
  __shared__ __align__(16) float tab[MT_FLOATS];
  __shared__ float la[256], lb[256];
  __shared__ int lastflag;

  const int tid = threadIdx.x;
  const int b   = blockIdx.x * 256 + tid;

  { // stage merged z-table only (6148 float4)
    const float4* s4 = (const float4*)tabsrc;
    float4* d4 = (float4*)tab;
    for (int i = tid; i < MT_FLOATS / 4; i += 256) d4[i] = s4[i];
  }
  __syncthreads();

  const float4* tab4 = (const float4*)tab;

  const float fb2s = fb2[0], hb2s = hb2[0], gb2s = gb2[0], pb2s = pb2[0];
  const float qw0 = qw[0], qw1 = qw[1], qb0 = qb[0], qb1 = qb[1];
  const float ns = noise_std[0];
  const float inv_ns = 1.0f / ns;
  const float nh_i2 = -0.5f * inv_ns * inv_ns;
  const float pm = pz0_mean[0], pls = pz0_logstd[0];

  auto lagr = [&](float c) {    // cubic Lagrange, nodes {-3,-1,1,3} (verified)
    const float c2 = c * c;
    const float p1 = c2 - 1.0f, p3 = c2 - 9.0f;
    return make_float4(p1 * (c - 3.0f) * (-1.0f / 48.0f),
                       p3 * (c - 1.0f) * ( 1.0f / 16.0f),
                       p3 * (c + 1.0f) * (-1.0f / 16.0f),
                       p1 * (c + 3.0f) * ( 1.0f / 48.0f));
  };
  auto hgp_exact = [&](float z, float& hv, float& gv, float& pv) {
    float sh = 0.f, sg = 0.f, sp = 0.f;
    for (int j = 0; j < 64; ++j) {
      sh = fmaf(sp_precise(fmaf(z, hw1[j], hb1[j])), hw2[j], sh);
      sg = fmaf(sp_precise(fmaf(z, gw1[j], gb1[j])), gw2[j], sg);
      sp = fmaf(sp_precise(fmaf(z, pw1[j], pb1[j])), pw2[j], sp);
    }
    hv = sh + hb2s;
    gv = 1.0f / (1.0f + expf(-(sg + gb2s)));
    pv = sp + pb2s;
  };
  auto f_exact = [&](float z, float c) {
    float s = 0.f;
    for (int j = 0; j < 64; ++j)
      s = fmaf(sp_precise(fmaf(z, fw1[j], fmaf(c, fw1[64 + j], fb1[j]))), fw2[j], s);
    return s + fb2s;
  };

  // merged two-tier index: one base, entries zi & zi+1 are 64B contiguous
  auto zidx = [&](float z, int& base4, float& frac, bool& inr) {
    const float s1 = fmaf(z, 8.0f, 1024.0f);        // tier1 (dz=1/8)
    const float s2 = fmaf(z, 0.0625f, 512.0f);      // tier2 (dz=16)
    const bool t1 = (s1 >= 0.0f) && (s1 <= 2048.0f);
    const bool t2 = (s2 >= 0.0f) && (s2 <= 1024.0f);
    inr = t1 || t2;
    const float sf = t1 ? s1 : fminf(fmaxf(s2, 0.0f), 1024.0f);
    const int fi = min((int)sf, t1 ? (NT1 - 2) : (NT2 - 2));
    base4 = (t1 ? 0 : T2_BASE4) + 2 * fi;
    frac = sf - (float)fi;
  };

  // ---- prologue ----
  const float x0 = xs[b];
  float x1 = xs[B_SZ + b];
  float x2 = xs[2 * B_SZ + b];
  const float c0v = ctx[b];
  float c_cur = ctx[B_SZ + b];
  float c_nxt = ctx[2 * B_SZ + b];
  const float qm  = fmaf(c0v, qw0, qb0);
  const float qls = fmaf(c0v, qw1, qb1);
  float z = fmaf(__expf(qls), eps0[b], qm);
  const float dqm = qm - pm;
  const float kl = (pls - qls)
                 + (__expf(2.0f * qls) + dqm * dqm) * (0.5f * __expf(-2.0f * pls))
                 - 0.5f;

  bool zin; int zb4; float zfr;
  float4 q0a, q0b, q1a, q1b;
  float hv, gv, pv;
  zidx(z, zb4, zfr, zin);
  q0a = tab4[zb4]; q0b = tab4[zb4 + 1]; q1a = tab4[zb4 + 2]; q1b = tab4[zb4 + 3];
  if (zin) {
    hv = fmaf(zfr, q1b.x - q0b.x, q0b.x);
    gv = fmaf(zfr, q1b.y - q0b.y, q0b.y);
    pv = fmaf(zfr, q1b.z - q0b.z, q0b.z);
  } else {
    hgp_exact(z, hv, gv, pv);
  }
  float lp_sum; { const float d = x0 - pv; lp_sum = nh_i2 * d * d; }
  float lr_sum = 0.0f;
  float dw_cur = dW[b];
  float dw_n1  = dW[B_SZ + b];
  float4 L = lagr(c_cur);
  bool cin = fabsf(c_cur) <= 3.0f;

  // ---- Euler-Maruyama scan ----
  for (int k = 0; k < T_SZ - 1; ++k) {
    const int   i3    = (k + 3 < T_SZ) ? (k + 3) : (T_SZ - 1);
    const float x3    = xs[i3 * B_SZ + b];
    const float c3    = ctx[i3 * B_SZ + b];
    const float dw_n2 = (k + 2 < T_SZ - 1) ? dW[(k + 2) * B_SZ + b] : 0.0f;
    const float dt    = ts[k + 1] - ts[k];
    const float sq    = SQRTF(dt);

    // f(z, c_cur): z-lerp of 4 c-node values, cubic in c (verified math)
    float fv;
    if (zin && cin) {
      const float n0 = fmaf(zfr, q1a.x - q0a.x, q0a.x);
      const float n1 = fmaf(zfr, q1a.y - q0a.y, q0a.y);
      const float n2 = fmaf(zfr, q1a.z - q0a.z, q0a.z);
      const float n3 = fmaf(zfr, q1a.w - q0a.w, q0a.w);
      fv = n0 * L.x + n1 * L.y + n2 * L.z + n3 * L.w;
    } else {
      fv = f_exact(z, c_cur);
    }

    const float gvs = fmaxf(gv, 1e-6f);
    const float uu = (fv - hv) * RCPF(gvs);   // feeds only lr_sum
    lr_sum = fmaf((0.5f * dt) * uu, uu, lr_sum);
    z = fmaf(gvs * dw_cur, sq, fmaf(fv, dt, z));

    // re-index at new z; 4 contiguous ds_read_b128 from one base
    zidx(z, zb4, zfr, zin);
    q0a = tab4[zb4]; q0b = tab4[zb4 + 1]; q1a = tab4[zb4 + 2]; q1b = tab4[zb4 + 3];
    if (zin) {
      hv = fmaf(zfr, q1b.x - q0b.x, q0b.x);
      gv = fmaf(zfr, q1b.y - q0b.y, q0b.y);
      pv = fmaf(zfr, q1b.z - q0b.z, q0b.z);
    } else {
      hgp_exact(z, hv, gv, pv);
    }

    // projector likelihood at t=k+1
    const float d = x1 - pv;
    lp_sum = fmaf(nh_i2 * d, d, lp_sum);

    // advance off-chain pipelines
    c_cur = c_nxt; L = lagr(c_cur); cin = fabsf(c_cur) <= 3.0f;
    c_nxt = c3;
    x1 = x2; x2 = x3;
    dw_cur = dw_n1; dw_n1 = dw_n2;
  }

  // ---- fused deterministic reduction (R10-verified pattern) ----
  la[tid] = lp_sum; lb[tid] = kl + lr_sum;
  __syncthreads();
  for (int s = 128; s > 0; s >>= 1) {
    if (tid < s) { la[tid] += la[tid + s]; lb[tid] += lb[tid + s]; }
    __syncthreads();
  }
  if (tid == 0) {
    partA[blockIdx.x] = la[0]; partB[blockIdx.x] = lb[0];
    __threadfence();
    lastflag = (atomicAdd(ctr, 1) == NBLK - 1) ? 1 : 0;
  }
  __syncthreads();
  if (lastflag) {
    __threadfence();
    la[tid] = (tid < NBLK) ? partA[tid] : 0.0f;
    lb[tid] = (tid < NBLK) ? partB[tid] : 0.0f;
    __syncthreads();
    for (int s = 128; s > 0; s >>= 1) {
      if (tid < s) { la[tid] += la[tid + s]; lb[tid] += lb[tid + s]; }
      __syncthreads();
    }
    if (tid == 0) {
      out[0] = la[0] / (float)B_SZ
             + (float)T_SZ * (-__logf(ns) - 0.9189385332046727f);
      out[1] = lb[0] / (float)B_SZ;
    }
  }
}

extern "C" void kernel_launch(void* const* d_in, const int* in_sizes, int n_in,
                              void* d_out, int out_size, void* d_ws, size_t ws_size,
                              hipStream_t stream) {
  const float* xs        = (const float*)d_in[0];
  const float* ts        = (const float*)d_in[1];
  const float* noise_std = (const float*)d_in[2];
  const float* eps0      = (const float*)d_in[3];
  const float* dW        = (const float*)d_in[4];
  const float* ew1 = (const float*)d_in[5];
  const float* eb1 = (const float*)d_in[6];
  const float* ew2 = (const float*)d_in[7];
  const float* eb2 = (const float*)d_in[8];
  const float* qw  = (const float*)d_in[9];
  const float* qb  = (const float*)d_in[10];
  const float* fw1 = (const float*)d_in[11];
  const float* fb1 = (const float*)d_in[12];
  const float* fw2 = (const float*)d_in[13];
  const float* fb2 = (const float*)d_in[14];
  const float* hw1 = (const float*)d_in[15];
  const float* hb1 = (const float*)d_in[16];
  const float* hw2 = (const float*)d_in[17];
  const float* hb2 = (const float*)d_in[18];
  const float* gw1 = (const float*)d_in[19];
  const float* gb1 = (const float*)d_in[20];
  const float* gw2 = (const float*)d_in[21];
  const float* gb2 = (const float*)d_in[22];
  const float* pw1 = (const float*)d_in[23];
  const float* pb1 = (const float*)d_in[24];
  const float* pw2 = (const float*)d_in[25];
  const float* pb2 = (const float*)d_in[26];
  const float* pz0_mean   = (const float*)d_in[27];
  const float* pz0_logstd = (const float*)d_in[28];
  float* out = (float*)d_out;

  float* tabs  = (float*)d_ws;                       // [TABG_FLOATS]
  int*   ctr   = (int*)(tabs + TABG_FLOATS);         // [1] (+pad to 4)
  float* partA = tabs + TABG_FLOATS + 4;             // [NBLK]
  float* partB = partA + NBLK;                       // [NBLK]
  float* ctxb  = tabs + TABG_FLOATS + 72;            // [T*B], 16B-aligned

  build_tabs<<<(NENT * 64 + 255) / 256, 256, 0, stream>>>(
      ew1, eb1, ew2, eb2, fw1, fb1, fw2, fb2,
      hw1, hb1, hw2, hb2, gw1, gb1, gw2, gb2,
      pw1, pb1, pw2, pb2, tabs, ctr);

  ctx_pre<<<(T_SZ * B_SZ) / 256, 256, 0, stream>>>(xs, tabs, ctxb);

  sde_scan<<<NBLK, 256, 0, stream>>>(
      xs, ts, noise_std, eps0, dW, ctxb, qw, qb,
      fw1, fb1, fw2, fb2, hw1, hb1, hw2, hb2,
      gw1, gb1, gw2, gb2, pw1, pb1, pw2, pb2,
      pz0_mean, pz0_logstd, tabs, ctr, partA, partB, out);
}

// Round 14
// 61.909 us; speedup vs baseline: 1.3602x; 1.1929x over previous
//
#include <hip/hip_runtime.h>
#include <math.h>

// LatentSDE (L=C=D=1, H=64), all nets tabulated, thread-per-b recurrence.
// R13 analysis: per-step stall = global loads prefetched only ~1 step ahead
// (L2/HBM latency lands in every step; R12's 1-wave/CU showed ~1455cy/step
// chain) + bank conflicts UP at 32B entry stride (4 bank-groups only).
// R14: (1) 4-deep register prefetch of xs/ctx/dW (macro-unrolled slots ->
// compile-time indices), refill k+4 issued at step k (~900cy slack);
// (2) 48B entry stride (8 bank-groups) with tier1 dz=1/4 (R8-verified) so
// the table stays 98.4KB LDS. Geometry 32x256 (R10-best). Numerics as
// R10-13 (absmax 0.0): tier1 z[-128,128]; tier2 z[-8192,8192] dz=16;
// exact-MLP fallback beyond; cubic Lagrange in c at nodes {-3,-1,1,3}.

#define B_SZ 8192
#define T_SZ 128
#define NBLK 32                  // scan blocks (256 thr each)

#define NT1 1025                 // tier1 entries (z in [-128,128], dz=1/4)
#define NT2 1025                 // tier2 entries (z in [-8192,8192], dz=16)
#define NEE 1024                 // encoder pairs (x in [-8,8], dx=1/64)
#define NENT (NT1 + NT2 + NEE)   // 3074 build entries (one wave each)

#define ENT_F4 3                       // 48B entry stride (bank spread)
#define MT_FLOATS (4 * ENT_F4 * (NT1 + NT2))  // 24600 floats = 98.4KB
#define T2_BASE4 (ENT_F4 * NT1)        // 3075
#define ET2G_OFF  MT_FLOATS            // et2 (global only), 2048 floats
#define TABG_FLOATS (MT_FLOATS + 2048) // 26648

#define NXI 1024
#define XSF 64.0f
#define XOF 512.0f

#if __has_builtin(__builtin_amdgcn_rcpf)
#define RCPF(x) __builtin_amdgcn_rcpf(x)
#else
#define RCPF(x) (1.0f / (x))
#endif
#if __has_builtin(__builtin_amdgcn_sqrtf)
#define SQRTF(x) __builtin_amdgcn_sqrtf(x)
#else
#define SQRTF(x) sqrtf(x)
#endif

__device__ __forceinline__ float sp_precise(float a) {
  return fmaxf(a, 0.0f) + log1pf(expf(-fabsf(a)));
}
__device__ __forceinline__ float wsum64(float v) {
  #pragma unroll
  for (int m = 1; m <= 32; m <<= 1) v += __shfl_xor(v, m);
  return v;
}

// ---------------- build: one wave per entry ----------------
__global__ __launch_bounds__(256) void build_tabs(
    const float* __restrict__ ew1, const float* __restrict__ eb1,
    const float* __restrict__ ew2, const float* __restrict__ eb2,
    const float* __restrict__ fw1, const float* __restrict__ fb1,
    const float* __restrict__ fw2, const float* __restrict__ fb2,
    const float* __restrict__ hw1, const float* __restrict__ hb1,
    const float* __restrict__ hw2, const float* __restrict__ hb2,
    const float* __restrict__ gw1, const float* __restrict__ gb1,
    const float* __restrict__ gw2, const float* __restrict__ gb2,
    const float* __restrict__ pw1, const float* __restrict__ pb1,
    const float* __restrict__ pw2, const float* __restrict__ pb2,
    float* __restrict__ tabs, int* __restrict__ ctr)
{
  const int gtid = blockIdx.x * 256 + threadIdx.x;
  if (gtid == 0) *ctr = 0;
  const int ent  = gtid >> 6;
  const int lane = threadIdx.x & 63;
  if (ent >= NENT) return;

  if (ent < NT1 + NT2) {
    const bool t1 = ent < NT1;
    const int  i  = t1 ? ent : (ent - NT1);
    const float z = t1 ? (-128.0f + (float)i * 0.25f)
                       : (-8192.0f + (float)i * 16.0f);
    const int base4 = (t1 ? 0 : T2_BASE4) + ENT_F4 * i;

    const float az = fmaf(z, fw1[lane], fb1[lane]);
    const float wc = fw1[64 + lane], w2 = fw2[lane];
    float s0 = sp_precise(fmaf(-3.0f, wc, az)) * w2;
    float s1 = sp_precise(fmaf(-1.0f, wc, az)) * w2;
    float s2 = sp_precise(fmaf( 1.0f, wc, az)) * w2;
    float s3 = sp_precise(fmaf( 3.0f, wc, az)) * w2;
    float sh = sp_precise(fmaf(z, hw1[lane], hb1[lane])) * hw2[lane];
    float sg = sp_precise(fmaf(z, gw1[lane], gb1[lane])) * gw2[lane];
    float sp = sp_precise(fmaf(z, pw1[lane], pb1[lane])) * pw2[lane];
    s0 = wsum64(s0); s1 = wsum64(s1); s2 = wsum64(s2); s3 = wsum64(s3);
    sh = wsum64(sh); sg = wsum64(sg); sp = wsum64(sp);
    if (lane == 0) {
      const float fb = fb2[0];
      ((float4*)tabs)[base4]     = make_float4(s0 + fb, s1 + fb, s2 + fb, s3 + fb);
      ((float4*)tabs)[base4 + 1] = make_float4(
          sh + hb2[0],
          1.0f / (1.0f + expf(-(sg + gb2[0]))),
          sp + pb2[0], 0.0f);
      ((float4*)tabs)[base4 + 2] = make_float4(0.f, 0.f, 0.f, 0.f);  // pad
    }
  } else {
    const int i = ent - (NT1 + NT2);
    const float x0 = -8.0f + (float)i * (1.0f / 64.0f);
    const float x1 = x0 + (1.0f / 64.0f);
    const float w = ew1[lane], bb = eb1[lane], w2 = ew2[lane];
    float s0 = sp_precise(fmaf(x0, w, bb)) * w2;
    float s1 = sp_precise(fmaf(x1, w, bb)) * w2;
    s0 = wsum64(s0); s1 = wsum64(s1);
    if (lane == 0) {
      const float eb = eb2[0];
      ((float2*)(tabs + ET2G_OFF))[i] = make_float2(s0 + eb, s1 + eb);
    }
  }
}

// ---------------- pre-pass: ctx[t,b] = enc(xs[t,b]) ----------------
__global__ __launch_bounds__(256) void ctx_pre(
    const float* __restrict__ xs, const float* __restrict__ tabs,
    float* __restrict__ ctx)
{
  const int i = blockIdx.x * 256 + threadIdx.x;
  const float2* et2 = (const float2*)(tabs + ET2G_OFF);
  const float s = fmaf(xs[i], XSF, XOF);
  const float sc = fminf(fmaxf(s, 0.0f), (float)(NXI - 1));
  const int ii = (int)sc;
  const float fr = s - (float)ii;
  const float2 e = et2[ii];
  ctx[i] = fmaf(fr, e.y - e.x, e.x);
}

// ---------------- scan ----------------
__global__ __launch_bounds__(256) void sde_scan(
    const float* __restrict__ xs, const float* __restrict__ ts,
    const float* __restrict__ noise_std, const float* __restrict__ eps0,
    const float* __restrict__ dW, const float* __restrict__ ctx,
    const float* __restrict__ qw,  const float* __restrict__ qb,
    const float* __restrict__ fw1, const float* __restrict__ fb1,
    const float* __restrict__ fw2, const float* __restrict__ fb2,
    const float* __restrict__ hw1, const float* __restrict__ hb1,
    const float* __restrict__ hw2, const float* __restrict__ hb2,
    const float* __restrict__ gw1, const float* __restrict__ gb1,
    const float* __restrict__ gw2, const float* __restrict__ gb2,
    const float* __restrict__ pw1, const float* __restrict__ pb1,
    const float* __restrict__ pw2, const float* __restrict__ pb2,
    const float* __restrict__ pz0_mean, const float* __restrict__ pz0_logstd,
    const float* __restrict__ tabsrc,
    int* __restrict__ ctr, float* __restrict__ partA, float* __restrict__ partB,
    float* __restrict__ out)
{
  __shared__ __align__(16) float tab[MT_FLOATS];
  __shared__ float la[256], lb[256];
  __shared__ int lastflag;

  const int tid = threadIdx.x;
  const int b   = blockIdx.x * 256 + tid;

  { // stage z-table
    const float4* s4 = (const float4*)tabsrc;
    float4* d4 = (float4*)tab;
    for (int i = tid; i < MT_FLOATS / 4; i += 256) d4[i] = s4[i];
  }
  __syncthreads();

  const float4* tab4 = (const float4*)tab;

  const float fb2s = fb2[0], hb2s = hb2[0], gb2s = gb2[0], pb2s = pb2[0];
  const float qw0 = qw[0], qw1 = qw[1], qb0 = qb[0], qb1 = qb[1];
  const float ns = noise_std[0];
  const float inv_ns = 1.0f / ns;
  const float nh_i2 = -0.5f * inv_ns * inv_ns;
  const float pm = pz0_mean[0], pls = pz0_logstd[0];

  auto lagr = [&](float c) {    // cubic Lagrange, nodes {-3,-1,1,3}
    const float c2 = c * c;
    const float p1 = c2 - 1.0f, p3 = c2 - 9.0f;
    return make_float4(p1 * (c - 3.0f) * (-1.0f / 48.0f),
                       p3 * (c - 1.0f) * ( 1.0f / 16.0f),
                       p3 * (c + 1.0f) * (-1.0f / 16.0f),
                       p1 * (c + 3.0f) * ( 1.0f / 48.0f));
  };
  auto hgp_exact = [&](float z_, float& hv_, float& gv_, float& pv_) {
    float sh = 0.f, sg = 0.f, sp = 0.f;
    for (int j = 0; j < 64; ++j) {
      sh = fmaf(sp_precise(fmaf(z_, hw1[j], hb1[j])), hw2[j], sh);
      sg = fmaf(sp_precise(fmaf(z_, gw1[j], gb1[j])), gw2[j], sg);
      sp = fmaf(sp_precise(fmaf(z_, pw1[j], pb1[j])), pw2[j], sp);
    }
    hv_ = sh + hb2s;
    gv_ = 1.0f / (1.0f + expf(-(sg + gb2s)));
    pv_ = sp + pb2s;
  };
  auto f_exact = [&](float z_, float c_) {
    float s = 0.f;
    for (int j = 0; j < 64; ++j)
      s = fmaf(sp_precise(fmaf(z_, fw1[j], fmaf(c_, fw1[64 + j], fb1[j]))), fw2[j], s);
    return s + fb2s;
  };
  auto zidx = [&](float z_, int& base4_, float& frac_, bool& inr_) {
    const float s1 = fmaf(z_, 4.0f, 512.0f);        // tier1 (dz=1/4)
    const float s2 = fmaf(z_, 0.0625f, 512.0f);     // tier2 (dz=16)
    const bool t1 = (s1 >= 0.0f) && (s1 <= 1024.0f);
    const bool t2 = (s2 >= 0.0f) && (s2 <= 1024.0f);
    inr_ = t1 || t2;
    const float sf = t1 ? s1 : fminf(fmaxf(s2, 0.0f), 1024.0f);
    const int fi = min((int)sf, 1023);
    base4_ = (t1 ? 0 : T2_BASE4) + ENT_F4 * fi;
    frac_ = sf - (float)fi;
  };

  // ---- prologue ----
  const float x0 = xs[b];
  const float c0v = ctx[b];
  const float qm  = fmaf(c0v, qw0, qb0);
  const float qls = fmaf(c0v, qw1, qb1);
  float z = fmaf(__expf(qls), eps0[b], qm);
  const float dqm = qm - pm;
  const float kl = (pls - qls)
                 + (__expf(2.0f * qls) + dqm * dqm) * (0.5f * __expf(-2.0f * pls))
                 - 0.5f;

  // 4-deep prefetch buffers: slot j holds {xs[(k+1)B+b], ctx[(k+1)B+b], dW[kB+b]}
  float xbuf0 = xs[1 * B_SZ + b], cbuf0 = ctx[1 * B_SZ + b], wbuf0 = dW[0 * B_SZ + b];
  float xbuf1 = xs[2 * B_SZ + b], cbuf1 = ctx[2 * B_SZ + b], wbuf1 = dW[1 * B_SZ + b];
  float xbuf2 = xs[3 * B_SZ + b], cbuf2 = ctx[3 * B_SZ + b], wbuf2 = dW[2 * B_SZ + b];
  float xbuf3 = xs[4 * B_SZ + b], cbuf3 = ctx[4 * B_SZ + b], wbuf3 = dW[3 * B_SZ + b];

  bool zin; int zb4; float zfr;
  float4 q0a, q0b, q1a, q1b;
  float hv, gv, pv;
  zidx(z, zb4, zfr, zin);
  q0a = tab4[zb4]; q0b = tab4[zb4 + 1];
  q1a = tab4[zb4 + ENT_F4]; q1b = tab4[zb4 + ENT_F4 + 1];
  if (zin) {
    hv = fmaf(zfr, q1b.x - q0b.x, q0b.x);
    gv = fmaf(zfr, q1b.y - q0b.y, q0b.y);
    pv = fmaf(zfr, q1b.z - q0b.z, q0b.z);
  } else {
    hgp_exact(z, hv, gv, pv);
  }
  float lp_sum; { const float d = x0 - pv; lp_sum = nh_i2 * d * d; }
  float lr_sum = 0.0f;

#define STEP(K, J) { \
    const float dt = ts[(K) + 1] - ts[(K)]; \
    const float sq = SQRTF(dt); \
    const float cc = cbuf##J; \
    const float4 L = lagr(cc); \
    const bool cin = fabsf(cc) <= 3.0f; \
    float fv; \
    if (zin && cin) { \
      const float n0 = fmaf(zfr, q1a.x - q0a.x, q0a.x); \
      const float n1 = fmaf(zfr, q1a.y - q0a.y, q0a.y); \
      const float n2 = fmaf(zfr, q1a.z - q0a.z, q0a.z); \
      const float n3 = fmaf(zfr, q1a.w - q0a.w, q0a.w); \
      fv = n0 * L.x + n1 * L.y + n2 * L.z + n3 * L.w; \
    } else { \
      fv = f_exact(z, cc); \
    } \
    const float gvs = fmaxf(gv, 1e-6f); \
    const float uu = (fv - hv) * RCPF(gvs); \
    lr_sum = fmaf((0.5f * dt) * uu, uu, lr_sum); \
    z = fmaf(gvs * wbuf##J, sq, fmaf(fv, dt, z)); \
    zidx(z, zb4, zfr, zin); \
    q0a = tab4[zb4]; q0b = tab4[zb4 + 1]; \
    q1a = tab4[zb4 + ENT_F4]; q1b = tab4[zb4 + ENT_F4 + 1]; \
    /* refill slot J for step K+4 (3+ steps of latency slack) */ \
    const int kk_ = (K) + 4; \
    const int ix_ = ((kk_ + 1 < T_SZ) ? kk_ + 1 : T_SZ - 1) * B_SZ + b; \
    const float xb_n = xs[ix_]; \
    const float cb_n = ctx[ix_]; \
    const float wb_n = (kk_ < T_SZ - 1) ? dW[kk_ * B_SZ + b] : 0.0f; \
    if (zin) { \
      hv = fmaf(zfr, q1b.x - q0b.x, q0b.x); \
      gv = fmaf(zfr, q1b.y - q0b.y, q0b.y); \
      pv = fmaf(zfr, q1b.z - q0b.z, q0b.z); \
    } else { \
      hgp_exact(z, hv, gv, pv); \
    } \
    const float d_ = xbuf##J - pv; \
    lp_sum = fmaf(nh_i2 * d_, d_, lp_sum); \
    xbuf##J = xb_n; cbuf##J = cb_n; wbuf##J = wb_n; \
  }

  // ---- Euler-Maruyama scan: 127 steps = 31*4 + 3 ----
  for (int k = 0; k < 124; k += 4) {
    STEP(k, 0); STEP(k + 1, 1); STEP(k + 2, 2); STEP(k + 3, 3);
  }
  STEP(124, 0); STEP(125, 1); STEP(126, 2);
#undef STEP

  // ---- fused deterministic reduction ----
  la[tid] = lp_sum; lb[tid] = kl + lr_sum;
  __syncthreads();
  for (int s = 128; s > 0; s >>= 1) {
    if (tid < s) { la[tid] += la[tid + s]; lb[tid] += lb[tid + s]; }
    __syncthreads();
  }
  if (tid == 0) {
    partA[blockIdx.x] = la[0]; partB[blockIdx.x] = lb[0];
    __threadfence();
    lastflag = (atomicAdd(ctr, 1) == NBLK - 1) ? 1 : 0;
  }
  __syncthreads();
  if (lastflag) {
    __threadfence();
    la[tid] = (tid < NBLK) ? partA[tid] : 0.0f;
    lb[tid] = (tid < NBLK) ? partB[tid] : 0.0f;
    __syncthreads();
    for (int s = 128; s > 0; s >>= 1) {
      if (tid < s) { la[tid] += la[tid + s]; lb[tid] += lb[tid + s]; }
      __syncthreads();
    }
    if (tid == 0) {
      out[0] = la[0] / (float)B_SZ
             + (float)T_SZ * (-__logf(ns) - 0.9189385332046727f);
      out[1] = lb[0] / (float)B_SZ;
    }
  }
}

extern "C" void kernel_launch(void* const* d_in, const int* in_sizes, int n_in,
                              void* d_out, int out_size, void* d_ws, size_t ws_size,
                              hipStream_t stream) {
  const float* xs        = (const float*)d_in[0];
  const float* ts        = (const float*)d_in[1];
  const float* noise_std = (const float*)d_in[2];
  const float* eps0      = (const float*)d_in[3];
  const float* dW        = (const float*)d_in[4];
  const float* ew1 = (const float*)d_in[5];
  const float* eb1 = (const float*)d_in[6];
  const float* ew2 = (const float*)d_in[7];
  const float* eb2 = (const float*)d_in[8];
  const float* qw  = (const float*)d_in[9];
  const float* qb  = (const float*)d_in[10];
  const float* fw1 = (const float*)d_in[11];
  const float* fb1 = (const float*)d_in[12];
  const float* fw2 = (const float*)d_in[13];
  const float* fb2 = (const float*)d_in[14];
  const float* hw1 = (const float*)d_in[15];
  const float* hb1 = (const float*)d_in[16];
  const float* hw2 = (const float*)d_in[17];
  const float* hb2 = (const float*)d_in[18];
  const float* gw1 = (const float*)d_in[19];
  const float* gb1 = (const float*)d_in[20];
  const float* gw2 = (const float*)d_in[21];
  const float* gb2 = (const float*)d_in[22];
  const float* pw1 = (const float*)d_in[23];
  const float* pb1 = (const float*)d_in[24];
  const float* pw2 = (const float*)d_in[25];
  const float* pb2 = (const float*)d_in[26];
  const float* pz0_mean   = (const float*)d_in[27];
  const float* pz0_logstd = (const float*)d_in[28];
  float* out = (float*)d_out;

  float* tabs  = (float*)d_ws;                       // [TABG_FLOATS]
  int*   ctr   = (int*)(tabs + TABG_FLOATS);         // [1] (+pad)
  float* partA = tabs + TABG_FLOATS + 4;             // [NBLK]
  float* partB = partA + NBLK;                       // [NBLK]
  float* ctxb  = tabs + TABG_FLOATS + 72;            // [T*B]

  build_tabs<<<(NENT * 64 + 255) / 256, 256, 0, stream>>>(
      ew1, eb1, ew2, eb2, fw1, fb1, fw2, fb2,
      hw1, hb1, hw2, hb2, gw1, gb1, gw2, gb2,
      pw1, pb1, pw2, pb2, tabs, ctr);

  ctx_pre<<<(T_SZ * B_SZ) / 256, 256, 0, stream>>>(xs, tabs, ctxb);

  sde_scan<<<NBLK, 256, 0, stream>>>(
      xs, ts, noise_std, eps0, dW, ctxb, qw, qb,
      fw1, fb1, fw2, fb2, hw1, hb1, hw2, hb2,
      gw1, gb1, gw2, gb2, pw1, pb1, pw2, pb2,
      pz0_mean, pz0_logstd, tabs, ctr, partA, partB, out);
}